// Round 5
// baseline (225.533 us; speedup 1.0000x reference)
//
#include <hip/hip_runtime.h>
#include <hip/hip_bf16.h>

#define B_ 8
#define E_ 2048
#define N_ 2048
#define F_ 128

#define BM 64      // hyperedge rows per block (4 m-tiles of 16)
#define MT 4       // m-tiles
#define BK 64      // K chunk (elements)
#define MP 136     // msg LDS pitch

using bf16x8 = __bf16 __attribute__((ext_vector_type(8)));
using fx4    = float __attribute__((ext_vector_type(4)));

static __device__ inline fx4 ntld4(const float* p) {
    return __builtin_nontemporal_load((const fx4*)p);   // ext_vector ok; HIP float4 is not
}

// ---------------- prep: node transpose + W convert (adj handled in main now) --------
__global__ __launch_bounds__(256) void prep_all(const float* __restrict__ node,
                                                const float* __restrict__ W,
                                                __bf16* __restrict__ nodeT,
                                                __bf16* __restrict__ Wb) {
    const int bid = blockIdx.x;
    const int t   = threadIdx.x;

    if (bid < 512) {
        // ---- node [B][N][F] f32 -> nodeT [B][F][N] bf16 (register transpose) ----
        // node reads are use-once -> nt; nodeT writes stay normal (want L2 residency).
        const int b  = bid & 7;
        const int n0 = (bid >> 3) * 32;
        const int f  = t & 127;
        const int nb = n0 + (t >> 7) * 16;
        const float* src = node + ((size_t)b * N_ + nb) * F_ + f;
        __bf16 h[16];
#pragma unroll
        for (int i = 0; i < 16; ++i)
            h[i] = (__bf16)__builtin_nontemporal_load(&src[(size_t)i * F_]);
        __bf16* dst = nodeT + ((size_t)b * F_ + f) * N_ + nb;
        *(uint4*)&dst[0] = *(const uint4*)&h[0];
        *(uint4*)&dst[8] = *(const uint4*)&h[8];
    } else {
        // ---- W f32 -> bf16 ----
        int idx = (bid - 512) * 256 + t;        // 0..4095
        float4 v = *(const float4*)&W[idx * 4];
        __bf16 o[4] = {(__bf16)v.x, (__bf16)v.y, (__bf16)v.z, (__bf16)v.w};
        *(uint2*)&Wb[idx * 4] = *(const uint2*)o;
    }
}

// ---------------- main: fused adj-stream + bitpack + GEMM1 + norm + GEMM2 -----------
// R0 structure (best measured: 212.8) + nontemporal adj stream. Theory: adj pushes
// 16.8 MB/XCD of use-once data through the 4 MiB L2 that must keep nodeT[b] (512 KB)
// resident for the Bs DMA of 32 co-located blocks; nt-marking adj stops the eviction.
__global__ __launch_bounds__(256, 1) void v2h_main(const float* __restrict__ adj,
                                                   const __bf16* __restrict__ nodeT,
                                                   const __bf16* __restrict__ Wb,
                                                   const float* __restrict__ bias,
                                                   float* __restrict__ out) {
    __shared__ __align__(16) __bf16 Bs[2][128][64];          // 32 KB, swizzled DMA layout
    __shared__ __align__(16) unsigned long long Abits[2][64];// 1 KB, dbuf bit tiles
    __shared__ __align__(16) float normS[BM];                // 256 B
    __shared__ __align__(16) __bf16 Ms[BM * MP];             // 17.4 KB

    const int t    = threadIdx.x;
    const int bid  = blockIdx.x;
    const int b    = bid & 7;            // batch -> XCD L2 locality for nodeT[b]
    const int e0   = (bid >> 3) * BM;    // bid>>3 in 0..31
    const int w    = t >> 6;             // wave id = f-group (32 cols)
    const int lane = t & 63;
    const int l15  = lane & 15;
    const int quad = lane >> 4;

    // adj-stream assignment: row arow = w*16 + (lane>>2), col-segment (lane&3)*16..+16
    const int ar   = lane >> 2;          // 0..15
    const int acs  = lane & 3;           // 0..3
    const int arow = w * 16 + ar;        // 0..63
    const float* aPtr = adj + ((size_t)b * E_ + e0 + arow) * N_ + acs * 16;

    const __bf16* nTB = nodeT + (size_t)b * F_ * N_;

    auto issue_dma = [&](int k0, int buf) {
#pragma unroll
        for (int p = 0; p < 4; ++p) {
            int idx = t + 256 * p;               // 0..1023
            int f   = idx >> 3;                  // 0..127
            int sl  = idx & 7;                   // LDS slot
            int g   = sl ^ (f & 7);              // global granule
            const __bf16* src = nTB + (size_t)f * N_ + k0 + g * 8;
            __bf16* dst = &Bs[buf][0][0] + (size_t)(w * 64 + 256 * p) * 8; // wave-uniform
            __builtin_amdgcn_global_load_lds(
                (const __attribute__((address_space(1))) void*)src,
                (__attribute__((address_space(3))) void*)dst, 16, 0, 0);
        }
    };

    auto cvt16 = [](fx4 v0, fx4 v1, fx4 v2, fx4 v3) -> unsigned {
        unsigned m = 0;
        m |= (v0[0] == -1.f) ? 1u     : 0u;
        m |= (v0[1] == -1.f) ? 2u     : 0u;
        m |= (v0[2] == -1.f) ? 4u     : 0u;
        m |= (v0[3] == -1.f) ? 8u     : 0u;
        m |= (v1[0] == -1.f) ? 16u    : 0u;
        m |= (v1[1] == -1.f) ? 32u    : 0u;
        m |= (v1[2] == -1.f) ? 64u    : 0u;
        m |= (v1[3] == -1.f) ? 128u   : 0u;
        m |= (v2[0] == -1.f) ? 256u   : 0u;
        m |= (v2[1] == -1.f) ? 512u   : 0u;
        m |= (v2[2] == -1.f) ? 1024u  : 0u;
        m |= (v2[3] == -1.f) ? 2048u  : 0u;
        m |= (v3[0] == -1.f) ? 4096u  : 0u;
        m |= (v3[1] == -1.f) ? 8192u  : 0u;
        m |= (v3[2] == -1.f) ? 16384u : 0u;
        m |= (v3[3] == -1.f) ? 32768u : 0u;
        return m;
    };

    auto unpack = [](unsigned byte) -> bf16x8 {
        union { unsigned u[4]; bf16x8 v; } r;
        r.u[0] = ((byte &   1u) ? 0x3F80u : 0u) | ((byte &   2u) ? 0x3F800000u : 0u);
        r.u[1] = ((byte &   4u) ? 0x3F80u : 0u) | ((byte &   8u) ? 0x3F800000u : 0u);
        r.u[2] = ((byte &  16u) ? 0x3F80u : 0u) | ((byte &  32u) ? 0x3F800000u : 0u);
        r.u[3] = ((byte &  64u) ? 0x3F80u : 0u) | ((byte & 128u) ? 0x3F800000u : 0u);
        return r.v;
    };

    fx4 acc[MT][2] = {};
    int cnt = 0;

    // ---- prologue: A(0) regs -> bits -> Abits[0]; B-DMA(0); A(1) regs in flight ----
    fx4 a0 = ntld4(aPtr + 0);
    fx4 a1 = ntld4(aPtr + 4);
    fx4 a2 = ntld4(aPtr + 8);
    fx4 a3 = ntld4(aPtr + 12);
    issue_dma(0, 0);
    {
        unsigned bits = cvt16(a0, a1, a2, a3);
        ((unsigned short*)&Abits[0][arow])[acs] = (unsigned short)bits;
        cnt += __popc(bits);
    }
    a0 = ntld4(aPtr + BK + 0);
    a1 = ntld4(aPtr + BK + 4);
    a2 = ntld4(aPtr + BK + 8);
    a3 = ntld4(aPtr + BK + 12);

#pragma unroll
    for (int m = 0; m < 32; ++m) {
        const int buf = m & 1;
        __syncthreads();   // drains B-DMA(m), adj regs; makes Abits[buf] visible

        if (m < 31)
            issue_dma((m + 1) * BK, buf ^ 1);
        if (m < 31) {
            unsigned bits = cvt16(a0, a1, a2, a3);   // A(m+1)
            ((unsigned short*)&Abits[buf ^ 1][arow])[acs] = (unsigned short)bits;
            cnt += __popc(bits);
        }
        if (m < 30) {
            const float* ap = aPtr + (m + 2) * BK;
            a0 = ntld4(ap + 0);
            a1 = ntld4(ap + 4);
            a2 = ntld4(ap + 8);
            a3 = ntld4(ap + 12);
        }

        // ---- A fragments from Abits[buf]: byte (ks*4+quad) of row-u64 ----
        bf16x8 af0[MT], af1[MT];
#pragma unroll
        for (int mt = 0; mt < MT; ++mt) {
            unsigned long long v = Abits[buf][mt * 16 + l15];
            unsigned lo = (unsigned)v, hi = (unsigned)(v >> 32);
            af0[mt] = unpack((lo >> (8 * quad)) & 255u);
            af1[mt] = unpack((hi >> (8 * quad)) & 255u);
        }

        // ---- B frag = row f, k-granule qg, at swizzled slot qg^(f&7); feeds 4 m-tiles
#pragma unroll
        for (int ft = 0; ft < 2; ++ft) {
            int f  = w * 32 + ft * 16 + l15;
            int q0 = quad ^ (f & 7);
            int q1 = (4 + quad) ^ (f & 7);
            bf16x8 b0 = *(const bf16x8*)&Bs[buf][f][q0 * 8];
#pragma unroll
            for (int mt = 0; mt < MT; ++mt)
                acc[mt][ft] = __builtin_amdgcn_mfma_f32_16x16x32_bf16(af0[mt], b0, acc[mt][ft], 0, 0, 0);
            bf16x8 b1 = *(const bf16x8*)&Bs[buf][f][q1 * 8];
#pragma unroll
            for (int mt = 0; mt < MT; ++mt)
                acc[mt][ft] = __builtin_amdgcn_mfma_f32_16x16x32_bf16(af1[mt], b1, acc[mt][ft], 0, 0, 0);
        }
    }

    // ---- norm: reduce count over the 4 col-segment threads of each row ----
    {
        float c = (float)cnt;
        c += __shfl_xor(c, 1);
        c += __shfl_xor(c, 2);
        if (acs == 0)
            normS[arow] = 1.f / fmaxf(c, 1.f);
    }
    __syncthreads();

    // ---- scale by 1/count, write msg bf16 to LDS in [m][f] layout ----
    const int rbase = quad * 4;
    float4 rn[MT];
#pragma unroll
    for (int mt = 0; mt < MT; ++mt)
        rn[mt] = *(const float4*)&normS[mt * 16 + rbase];

#pragma unroll
    for (int ft = 0; ft < 2; ++ft) {
        int fcol = w * 32 + ft * 16 + l15;
#pragma unroll
        for (int mt = 0; mt < MT; ++mt) {
            const float* rr = (const float*)&rn[mt];
#pragma unroll
            for (int r = 0; r < 4; ++r)
                Ms[(mt * 16 + rbase + r) * MP + fcol] = (__bf16)(acc[mt][ft][r] * rr[r]);
        }
    }
    __syncthreads();

    // ---- second GEMM: out[m][g] = sum_f msg[m][f] * W[g][f]; W direct from L2 ----
    fx4 acc2[MT][2] = {};
#pragma unroll
    for (int ks = 0; ks < 4; ++ks) {
        bf16x8 afm[MT];
#pragma unroll
        for (int mt = 0; mt < MT; ++mt)
            afm[mt] = *(const bf16x8*)&Ms[(mt * 16 + l15) * MP + ks * 32 + quad * 8];
#pragma unroll
        for (int gt = 0; gt < 2; ++gt) {
            int g = w * 32 + gt * 16 + l15;
            bf16x8 wfr = *(const bf16x8*)&Wb[(size_t)g * F_ + ks * 32 + quad * 8];
#pragma unroll
            for (int mt = 0; mt < MT; ++mt)
                acc2[mt][gt] = __builtin_amdgcn_mfma_f32_16x16x32_bf16(afm[mt], wfr, acc2[mt][gt], 0, 0, 0);
        }
    }

    // ---- bias + relu + store (all m-tiles); out is use-once -> nt stores ----
#pragma unroll
    for (int gt = 0; gt < 2; ++gt) {
        int g = w * 32 + gt * 16 + l15;
        float bb = bias[g];
#pragma unroll
        for (int mt = 0; mt < MT; ++mt) {
#pragma unroll
            for (int r = 0; r < 4; ++r) {
                int e = e0 + mt * 16 + rbase + r;
                float v = acc2[mt][gt][r] + bb;
                __builtin_nontemporal_store(fmaxf(v, 0.f),
                                            &out[((size_t)b * E_ + e) * F_ + g]);
            }
        }
    }
}

extern "C" void kernel_launch(void* const* d_in, const int* in_sizes, int n_in,
                              void* d_out, int out_size, void* d_ws, size_t ws_size,
                              hipStream_t stream) {
    const float* node = (const float*)d_in[0];   // [B,N,F]
    const float* adj  = (const float*)d_in[1];   // [B,E,N]
    const float* W    = (const float*)d_in[2];   // [F,F]
    const float* bias = (const float*)d_in[3];   // [F]
    float* out = (float*)d_out;                  // [B,E,F]

    char* ws = (char*)d_ws;
    __bf16* nodeT = (__bf16*)ws;                        // 8 MB
    __bf16* Wb    = (__bf16*)(ws + 8 * 1024 * 1024);    // 32 KB

    prep_all<<<528, 256, 0, stream>>>(node, W, nodeT, Wb);
    v2h_main<<<256, 256, 0, stream>>>(adj, nodeT, Wb, bias, out);
}

// Round 6
// 213.189 us; speedup vs baseline: 1.0579x; 1.0579x over previous
//
#include <hip/hip_runtime.h>
#include <hip/hip_bf16.h>

#define B_ 8
#define E_ 2048
#define N_ 2048
#define F_ 128

#define BM 64      // hyperedge rows per block (4 m-tiles of 16)
#define MT 4       // m-tiles
#define BK 64      // K chunk (elements)
#define MP 136     // msg LDS pitch

using bf16x8 = __bf16 __attribute__((ext_vector_type(8)));
using fx4    = float __attribute__((ext_vector_type(4)));

// ---------------- prep: node transpose + W convert (adj handled in main now) --------
__global__ __launch_bounds__(256) void prep_all(const float* __restrict__ node,
                                                const float* __restrict__ W,
                                                __bf16* __restrict__ nodeT,
                                                __bf16* __restrict__ Wb) {
    const int bid = blockIdx.x;
    const int t   = threadIdx.x;

    if (bid < 512) {
        // ---- node [B][N][F] f32 -> nodeT [B][F][N] bf16 (register transpose) ----
        const int b  = bid & 7;
        const int n0 = (bid >> 3) * 32;
        const int f  = t & 127;
        const int nb = n0 + (t >> 7) * 16;
        const float* src = node + ((size_t)b * N_ + nb) * F_ + f;
        __bf16 h[16];
#pragma unroll
        for (int i = 0; i < 16; ++i)
            h[i] = (__bf16)src[(size_t)i * F_];
        __bf16* dst = nodeT + ((size_t)b * F_ + f) * N_ + nb;
        *(uint4*)&dst[0] = *(const uint4*)&h[0];
        *(uint4*)&dst[8] = *(const uint4*)&h[8];
    } else {
        // ---- W f32 -> bf16 ----
        int idx = (bid - 512) * 256 + t;        // 0..4095
        float4 v = *(const float4*)&W[idx * 4];
        __bf16 o[4] = {(__bf16)v.x, (__bf16)v.y, (__bf16)v.z, (__bf16)v.w};
        *(uint2*)&Wb[idx * 4] = *(const uint2*)o;
    }
}

// ---------------- main: fused adj-stream + bitpack + GEMM1 + norm + GEMM2 -----------
// R0 structure — best measured (212.8 µs). Five perturbations all measured worse or
// neutral: BM=32/2-blocks-per-CU (223.5), counted-vmcnt T4 (215.7), lane-contiguous
// adj remap (218.8), nontemporal adj/out (225.5). Keep as-is.
__global__ __launch_bounds__(256, 1) void v2h_main(const float* __restrict__ adj,
                                                   const __bf16* __restrict__ nodeT,
                                                   const __bf16* __restrict__ Wb,
                                                   const float* __restrict__ bias,
                                                   float* __restrict__ out) {
    __shared__ __align__(16) __bf16 Bs[2][128][64];          // 32 KB, swizzled DMA layout
    __shared__ __align__(16) unsigned long long Abits[2][64];// 1 KB, dbuf bit tiles
    __shared__ __align__(16) float normS[BM];                // 256 B
    __shared__ __align__(16) __bf16 Ms[BM * MP];             // 17.4 KB

    const int t    = threadIdx.x;
    const int bid  = blockIdx.x;
    const int b    = bid & 7;            // batch -> XCD L2 locality for nodeT[b]
    const int e0   = (bid >> 3) * BM;    // bid>>3 in 0..31
    const int w    = t >> 6;             // wave id = f-group (32 cols)
    const int lane = t & 63;
    const int l15  = lane & 15;
    const int quad = lane >> 4;

    // adj-stream assignment: row arow = w*16 + (lane>>2), col-segment (lane&3)*16..+16
    const int ar   = lane >> 2;          // 0..15
    const int acs  = lane & 3;           // 0..3
    const int arow = w * 16 + ar;        // 0..63
    const float* aPtr = adj + ((size_t)b * E_ + e0 + arow) * N_ + acs * 16;

    const __bf16* nTB = nodeT + (size_t)b * F_ * N_;

    auto issue_dma = [&](int k0, int buf) {
#pragma unroll
        for (int p = 0; p < 4; ++p) {
            int idx = t + 256 * p;               // 0..1023
            int f   = idx >> 3;                  // 0..127
            int sl  = idx & 7;                   // LDS slot
            int g   = sl ^ (f & 7);              // global granule
            const __bf16* src = nTB + (size_t)f * N_ + k0 + g * 8;
            __bf16* dst = &Bs[buf][0][0] + (size_t)(w * 64 + 256 * p) * 8; // wave-uniform
            __builtin_amdgcn_global_load_lds(
                (const __attribute__((address_space(1))) void*)src,
                (__attribute__((address_space(3))) void*)dst, 16, 0, 0);
        }
    };

    auto cvt16 = [](float4 v0, float4 v1, float4 v2, float4 v3) -> unsigned {
        unsigned m = 0;
        m |= (v0.x == -1.f) ? 1u     : 0u;
        m |= (v0.y == -1.f) ? 2u     : 0u;
        m |= (v0.z == -1.f) ? 4u     : 0u;
        m |= (v0.w == -1.f) ? 8u     : 0u;
        m |= (v1.x == -1.f) ? 16u    : 0u;
        m |= (v1.y == -1.f) ? 32u    : 0u;
        m |= (v1.z == -1.f) ? 64u    : 0u;
        m |= (v1.w == -1.f) ? 128u   : 0u;
        m |= (v2.x == -1.f) ? 256u   : 0u;
        m |= (v2.y == -1.f) ? 512u   : 0u;
        m |= (v2.z == -1.f) ? 1024u  : 0u;
        m |= (v2.w == -1.f) ? 2048u  : 0u;
        m |= (v3.x == -1.f) ? 4096u  : 0u;
        m |= (v3.y == -1.f) ? 8192u  : 0u;
        m |= (v3.z == -1.f) ? 16384u : 0u;
        m |= (v3.w == -1.f) ? 32768u : 0u;
        return m;
    };

    auto unpack = [](unsigned byte) -> bf16x8 {
        union { unsigned u[4]; bf16x8 v; } r;
        r.u[0] = ((byte &   1u) ? 0x3F80u : 0u) | ((byte &   2u) ? 0x3F800000u : 0u);
        r.u[1] = ((byte &   4u) ? 0x3F80u : 0u) | ((byte &   8u) ? 0x3F800000u : 0u);
        r.u[2] = ((byte &  16u) ? 0x3F80u : 0u) | ((byte &  32u) ? 0x3F800000u : 0u);
        r.u[3] = ((byte &  64u) ? 0x3F80u : 0u) | ((byte & 128u) ? 0x3F800000u : 0u);
        return r.v;
    };

    fx4 acc[MT][2] = {};
    int cnt = 0;

    // ---- prologue: A(0) regs -> bits -> Abits[0]; B-DMA(0); A(1) regs in flight ----
    float4 a0 = *(const float4*)(aPtr + 0);
    float4 a1 = *(const float4*)(aPtr + 4);
    float4 a2 = *(const float4*)(aPtr + 8);
    float4 a3 = *(const float4*)(aPtr + 12);
    issue_dma(0, 0);
    {
        unsigned bits = cvt16(a0, a1, a2, a3);
        ((unsigned short*)&Abits[0][arow])[acs] = (unsigned short)bits;
        cnt += __popc(bits);
    }
    a0 = *(const float4*)(aPtr + BK + 0);
    a1 = *(const float4*)(aPtr + BK + 4);
    a2 = *(const float4*)(aPtr + BK + 8);
    a3 = *(const float4*)(aPtr + BK + 12);

#pragma unroll
    for (int m = 0; m < 32; ++m) {
        const int buf = m & 1;
        __syncthreads();   // drains B-DMA(m), adj regs; makes Abits[buf] visible

        if (m < 31)
            issue_dma((m + 1) * BK, buf ^ 1);
        if (m < 31) {
            unsigned bits = cvt16(a0, a1, a2, a3);   // A(m+1)
            ((unsigned short*)&Abits[buf ^ 1][arow])[acs] = (unsigned short)bits;
            cnt += __popc(bits);
        }
        if (m < 30) {
            const float* ap = aPtr + (m + 2) * BK;
            a0 = *(const float4*)(ap + 0);
            a1 = *(const float4*)(ap + 4);
            a2 = *(const float4*)(ap + 8);
            a3 = *(const float4*)(ap + 12);
        }

        // ---- A fragments from Abits[buf]: byte (ks*4+quad) of row-u64 ----
        bf16x8 af0[MT], af1[MT];
#pragma unroll
        for (int mt = 0; mt < MT; ++mt) {
            unsigned long long v = Abits[buf][mt * 16 + l15];
            unsigned lo = (unsigned)v, hi = (unsigned)(v >> 32);
            af0[mt] = unpack((lo >> (8 * quad)) & 255u);
            af1[mt] = unpack((hi >> (8 * quad)) & 255u);
        }

        // ---- B frag = row f, k-granule qg, at swizzled slot qg^(f&7); feeds 4 m-tiles
#pragma unroll
        for (int ft = 0; ft < 2; ++ft) {
            int f  = w * 32 + ft * 16 + l15;
            int q0 = quad ^ (f & 7);
            int q1 = (4 + quad) ^ (f & 7);
            bf16x8 b0 = *(const bf16x8*)&Bs[buf][f][q0 * 8];
#pragma unroll
            for (int mt = 0; mt < MT; ++mt)
                acc[mt][ft] = __builtin_amdgcn_mfma_f32_16x16x32_bf16(af0[mt], b0, acc[mt][ft], 0, 0, 0);
            bf16x8 b1 = *(const bf16x8*)&Bs[buf][f][q1 * 8];
#pragma unroll
            for (int mt = 0; mt < MT; ++mt)
                acc[mt][ft] = __builtin_amdgcn_mfma_f32_16x16x32_bf16(af1[mt], b1, acc[mt][ft], 0, 0, 0);
        }
    }

    // ---- norm: reduce count over the 4 col-segment threads of each row ----
    {
        float c = (float)cnt;
        c += __shfl_xor(c, 1);
        c += __shfl_xor(c, 2);
        if (acs == 0)
            normS[arow] = 1.f / fmaxf(c, 1.f);
    }
    __syncthreads();

    // ---- scale by 1/count, write msg bf16 to LDS in [m][f] layout ----
    const int rbase = quad * 4;
    float4 rn[MT];
#pragma unroll
    for (int mt = 0; mt < MT; ++mt)
        rn[mt] = *(const float4*)&normS[mt * 16 + rbase];

#pragma unroll
    for (int ft = 0; ft < 2; ++ft) {
        int fcol = w * 32 + ft * 16 + l15;
#pragma unroll
        for (int mt = 0; mt < MT; ++mt) {
            const float* rr = (const float*)&rn[mt];
#pragma unroll
            for (int r = 0; r < 4; ++r)
                Ms[(mt * 16 + rbase + r) * MP + fcol] = (__bf16)(acc[mt][ft][r] * rr[r]);
        }
    }
    __syncthreads();

    // ---- second GEMM: out[m][g] = sum_f msg[m][f] * W[g][f]; W direct from L2 ----
    fx4 acc2[MT][2] = {};
#pragma unroll
    for (int ks = 0; ks < 4; ++ks) {
        bf16x8 afm[MT];
#pragma unroll
        for (int mt = 0; mt < MT; ++mt)
            afm[mt] = *(const bf16x8*)&Ms[(mt * 16 + l15) * MP + ks * 32 + quad * 8];
#pragma unroll
        for (int gt = 0; gt < 2; ++gt) {
            int g = w * 32 + gt * 16 + l15;
            bf16x8 wfr = *(const bf16x8*)&Wb[(size_t)g * F_ + ks * 32 + quad * 8];
#pragma unroll
            for (int mt = 0; mt < MT; ++mt)
                acc2[mt][gt] = __builtin_amdgcn_mfma_f32_16x16x32_bf16(afm[mt], wfr, acc2[mt][gt], 0, 0, 0);
        }
    }

    // ---- bias + relu + store (all m-tiles) ----
#pragma unroll
    for (int gt = 0; gt < 2; ++gt) {
        int g = w * 32 + gt * 16 + l15;
        float bb = bias[g];
#pragma unroll
        for (int mt = 0; mt < MT; ++mt) {
#pragma unroll
            for (int r = 0; r < 4; ++r) {
                int e = e0 + mt * 16 + rbase + r;
                float v = acc2[mt][gt][r] + bb;
                out[((size_t)b * E_ + e) * F_ + g] = fmaxf(v, 0.f);
            }
        }
    }
}

extern "C" void kernel_launch(void* const* d_in, const int* in_sizes, int n_in,
                              void* d_out, int out_size, void* d_ws, size_t ws_size,
                              hipStream_t stream) {
    const float* node = (const float*)d_in[0];   // [B,N,F]
    const float* adj  = (const float*)d_in[1];   // [B,E,N]
    const float* W    = (const float*)d_in[2];   // [F,F]
    const float* bias = (const float*)d_in[3];   // [F]
    float* out = (float*)d_out;                  // [B,E,F]

    char* ws = (char*)d_ws;
    __bf16* nodeT = (__bf16*)ws;                        // 8 MB
    __bf16* Wb    = (__bf16*)(ws + 8 * 1024 * 1024);    // 32 KB

    prep_all<<<528, 256, 0, stream>>>(node, W, nodeT, Wb);
    v2h_main<<<256, 256, 0, stream>>>(adj, nodeT, Wb, bias, out);
}